// Round 8
// baseline (206.776 us; speedup 1.0000x reference)
//
#include <hip/hip_runtime.h>
#include <stdint.h>

#define NHEAD 12
#define DH 64
#define BATCH 4
#define SEQ 2048
#define CDIM 768
#define MROWS (BATCH*SEQ)   // 8192

typedef __attribute__((ext_vector_type(8))) short short8;
typedef __attribute__((ext_vector_type(4))) float floatx4;
typedef __attribute__((ext_vector_type(16))) float floatx16;
typedef unsigned int u32;

template<int N> struct IC { static constexpr int v = N; };

__device__ inline unsigned short f2bf(float f) {
    union { float f; unsigned u; } v; v.f = f;
    unsigned r = v.u + 0x7FFFu + ((v.u >> 16) & 1u);
    return (unsigned short)(r >> 16);
}

__device__ __forceinline__ u32 pk_bf16(float a, float b) {
    u32 d;
    asm("v_cvt_pk_bf16_f32 %0, %1, %2" : "=v"(d) : "v"(a), "v"(b));
    return d;
}

__device__ __forceinline__ void async_cp16(const unsigned short* g, unsigned short* l) {
    __builtin_amdgcn_global_load_lds(
        (const __attribute__((address_space(1))) u32*)g,
        (__attribute__((address_space(3))) u32*)l, 16, 0, 0);
}

template<int N> __device__ __forceinline__ void waitcnt_vm() {
    if constexpr (N == 0)      asm volatile("s_waitcnt vmcnt(0)" ::: "memory");
    else if constexpr (N == 3) asm volatile("s_waitcnt vmcnt(3)" ::: "memory");
    else if constexpr (N == 4) asm volatile("s_waitcnt vmcnt(4)" ::: "memory");
}

// ---------------- fused prep: x->bf16, w_attn^T->bf16, w_proj^T->bf16 -------
__device__ __forceinline__ void transpose_tile(
    const float* __restrict__ in, unsigned short* __restrict__ out,
    int K, int N, int k0, int n0, unsigned short (*T)[72]) {
    const int t = threadIdx.x;
    const int nc = t & 63, kw = t >> 6;
    for (int i = 0; i < 16; i++) {
        const int kr = kw + i * 4;
        T[nc][kr] = f2bf(in[(size_t)(k0 + kr) * N + n0 + nc]);
    }
    __syncthreads();
    const int row = t >> 2, seg = t & 3;
    uint4 a = *(const uint4*)&T[row][seg * 16];
    uint4 b2 = *(const uint4*)&T[row][seg * 16 + 8];
    unsigned short* o = &out[(size_t)(n0 + row) * K + k0 + seg * 16];
    *(uint4*)o = a;
    *(uint4*)(o + 8) = b2;
}

__global__ __launch_bounds__(256) void prep_kernel(
    const float* __restrict__ x,      unsigned short* __restrict__ xb,
    const float* __restrict__ wa,     unsigned short* __restrict__ wta,
    const float* __restrict__ wp,     unsigned short* __restrict__ wtp) {
    __shared__ unsigned short T[64][72];
    const int lin = blockIdx.x;
    if (lin < 6144) {                      // convert x: 1024 elems/block
        const int i = (lin * 256 + threadIdx.x) * 4;
        float4 f = *(const float4*)(x + i);
        union { unsigned short s[4]; uint2 u; } p;
        p.s[0] = f2bf(f.x); p.s[1] = f2bf(f.y);
        p.s[2] = f2bf(f.z); p.s[3] = f2bf(f.w);
        *(uint2*)(xb + i) = p.u;
    } else if (lin < 6144 + 432) {         // w_attn^T (768 x 2304)
        const int t2 = lin - 6144;
        transpose_tile(wa, wta, CDIM, 3 * CDIM, (t2 % 12) * 64, (t2 / 12) * 64, T);
    } else {                               // w_proj^T (768 x 768)
        const int t3 = lin - 6576;
        transpose_tile(wp, wtp, CDIM, CDIM, (t3 % 12) * 64, (t3 / 12) * 64, T);
    }
}

// ---------------- GEMM v2: 2-buffer ring + XCD-chunked block swizzle ---------
// Theory (r6): latency/residency-bound (MfmaUtil 21%, HBM 16%, per-iter wall
// ~1.2k cy vs ~250 cy issue). (1) ring 3->2 buffers cuts LDS 48->34/24 KB ->
// 4-6 blocks/CU; hazard structure identical to attn v12/v13 (verified): the
// buffer written at iter k (CUR^1) was last read at iter k-1, all readers
// passed the barrier. (2) bijective XCD-chunk swizzle (nwg%8==0): each XCD
// owns a contiguous lin-range -> B panels L2-resident per XCD, A re-reads
// L3-served; attacks the vmcnt stall directly.
// MODE 0: fp32 C. MODE 1: QKV epilogue; V-part blocks transpose via LDS.
template<int MODE, int KD, int BM, int BN>
__global__ __launch_bounds__(256) void gemm_bf16(
    const unsigned short* __restrict__ A,
    const unsigned short* __restrict__ BT,
    const float* __restrict__ bias,
    float* __restrict__ Cout,
    unsigned short* __restrict__ Qout,
    unsigned short* __restrict__ Kout,
    unsigned short* __restrict__ VTout,
    int Ndim)
{
    constexpr int TM = BM / 32, TN = BN / 32;
    constexpr int CHA = BM / 64, CHB = BN / 64;
    constexpr int RING = 2 * (BM + BN) * 32;            // shorts
    constexpr int SCR  = (MODE == 1) ? 4 * 64 * 68 : 0; // epilogue scratch
    constexpr int SHSZ = RING > SCR ? RING : SCR;
    __shared__ unsigned short SH[SHSZ];
    auto As = [&](int b2) { return &SH[b2 * BM * 32]; };
    auto Bs = [&](int b2) { return &SH[2 * BM * 32 + b2 * BN * 32]; };

    const int tid  = threadIdx.x;
    const int wave = tid >> 6;
    const int lane = tid & 63;
    const int l16  = lane & 15;
    const int quad = lane >> 4;
    const int wm = wave >> 1, wn = wave & 1;

    // bijective XCD-chunk swizzle (m204 simple form; nwg % 8 == 0)
    const int gx  = gridDim.x;
    const int nwg = gx * gridDim.y;
    int lin = blockIdx.x + blockIdx.y * gx;
    lin = (lin & 7) * (nwg >> 3) + (lin >> 3);
    const int m0 = (lin % gx) * BM;
    const int n0 = (lin / gx) * BN;

    const int rloc = lane >> 2;
    const int gs   = (((lane & 3) ^ (rloc & 3) ^ ((rloc >> 2) & 3))) * 8;
    const int pg   = ((quad ^ (l16 & 3) ^ ((l16 >> 2) & 3))) * 8;

    floatx4 acc[TM][TN];
    for (int i = 0; i < TM; i++)
        for (int j = 0; j < TN; j++) acc[i][j] = (floatx4)0.0f;

    constexpr int NIT = KD / 32;

    auto stageTo = [&](int s, int buf) {
        const int koff = s * 32;
        for (int ch = 0; ch < CHA; ch++) {
            const int row = wave * CHA * 16 + ch * 16 + rloc;
            async_cp16(&A[(size_t)(m0 + row) * KD + koff + gs],
                       &As(buf)[(wave * CHA + ch) * 512]);
        }
        for (int ch = 0; ch < CHB; ch++) {
            const int row = wave * CHB * 16 + ch * 16 + rloc;
            async_cp16(&BT[(size_t)(n0 + row) * KD + koff + gs],
                       &Bs(buf)[(wave * CHB + ch) * 512]);
        }
    };
    stageTo(0, 0);

    for (int it = 0; it < NIT; it++) {
        waitcnt_vm<0>();
        asm volatile("s_barrier" ::: "memory");
        if (it + 1 < NIT) stageTo(it + 1, (it + 1) & 1);
        const int buf = it & 1;
        short8 a[TM], b[TN];
        for (int i = 0; i < TM; i++)
            a[i] = *(const short8*)&As(buf)[(wm * (BM / 2) + i * 16 + l16) * 32 + pg];
        for (int j = 0; j < TN; j++)
            b[j] = *(const short8*)&Bs(buf)[(wn * (BN / 2) + j * 16 + l16) * 32 + pg];
        for (int i = 0; i < TM; i++)
            for (int j = 0; j < TN; j++)
                acc[i][j] = __builtin_amdgcn_mfma_f32_16x16x32_bf16(
                    a[i], b[j], acc[i][j], 0, 0, 0);
    }

    const float QSCALE = 0.18033688011112042f;   // 0.125 * log2(e)

    if (MODE == 1 && (n0 / CDIM) == 2) {
        // ---- V blocks: transpose 64x64 wave tile via LDS, coalesced VT ----
        __syncthreads();                           // done reading SH
        unsigned short* scr = &SH[wave * (64 * 68)];
        for (int i = 0; i < TM; i++) {
            const int tl = i * 16 + quad * 4;
            for (int j = 0; j < TN; j++) {
                const int dl = j * 16 + l16;
                const float bv = bias[n0 + wn * 64 + j * 16 + l16];
                uint2 u;
                u.x = pk_bf16(acc[i][j][0] + bv, acc[i][j][1] + bv);
                u.y = pk_bf16(acc[i][j][2] + bv, acc[i][j][3] + bv);
                *(uint2*)&scr[dl * 68 + tl] = u;
            }
        }
        const int b_ = m0 >> 11;
        const int tg = (m0 & 2047) + wm * 64;
        const int h  = (n0 - 2 * CDIM + wn * 64) >> 6;
        const size_t rowbase = ((size_t)(b_ * NHEAD + h)) * DH;
        for (int p = 0; p < 8; p++) {
            const int d  = p * 8 + (lane >> 3);
            const int tc = (lane & 7) * 8;
            uint4 v = *(const uint4*)&scr[d * 68 + tc];
            *(uint4*)&VTout[(rowbase + d) * SEQ + tg + tc] = v;
        }
        return;
    }

    for (int i = 0; i < TM; i++) {
        const int mbase = m0 + wm * (BM / 2) + i * 16 + quad * 4;
        for (int j = 0; j < TN; j++) {
            const int ncj  = n0 + wn * (BN / 2) + j * 16;
            const int ncol = ncj + l16;
            const float bv = bias[ncol];
            for (int r = 0; r < 4; r++) {
                const int m = mbase + r;
                const float v = acc[i][j][r] + bv;
                if (MODE == 0) {
                    Cout[(size_t)m * Ndim + ncol] = v;
                } else {
                    const int part = ncj / CDIM;   // 0 or 1 here
                    const int c = ncol - part * CDIM;
                    const int hh = c >> 6, d = c & 63;
                    const int b_ = m >> 11, t = m & 2047;
                    const size_t bh = (size_t)(b_ * NHEAD + hh);
                    if (part == 0)
                        Qout[(bh * SEQ + t) * DH + d] = f2bf(v * QSCALE);
                    else
                        Kout[(bh * SEQ + t) * DH + d] = f2bf(v);
                }
            }
        }
    }
}

// ---------------- flash attention v13 (verified r6): 1536 single-pass blocks -
__global__ __launch_bounds__(256) void attn_kernel(
    const unsigned short* __restrict__ Q,
    const unsigned short* __restrict__ K,
    const unsigned short* __restrict__ VT,
    unsigned short* __restrict__ O)
{
    __shared__ unsigned short Kl[2][2][64 * 32];   // [buf][d-half][key row][32]
    __shared__ unsigned short Vl[2][2][64 * 32];   // [buf][key-half][d row][32]

    const int tid  = threadIdx.x;
    const int wave = tid >> 6;
    const int lane = tid & 63;
    const int rl   = lane & 31;
    const int hi   = lane >> 5;
    const int qg   = wave >> 1;         // q-group: rows qg*32..+31 of the 64
    const int ks   = wave & 1;          // key-split: keys ks*32..+31 of tile

    const int lin = blockIdx.x;         // 0..1535
    const int j   = lin >> 3;           // 0..191
    const int bh  = (j % 6) * 8 + (lin & 7);   // XCD-pinned: bh === lin (mod 8)
    const int qtile = 31 - (j / 6);            // heavy tiles dispatched first
    const int h = bh % NHEAD, b = bh / NHEAD;

    const unsigned short* Qp = Q  + (size_t)bh * SEQ * DH;
    const unsigned short* Kp = K  + (size_t)bh * SEQ * DH;
    const unsigned short* Vp = VT + (size_t)bh * DH * SEQ;

    const int rloc  = lane >> 2;
    const int gofsK = ((lane & 3) ^ (rloc & 3) ^ ((rloc >> 2) & 3)) * 8;
    const int krow  = wave * 16 + rloc;
    const int swz   = (rl & 3) ^ ((rl >> 2) & 3);   // group unswizzle

    // bf16 ones vector (B operand for row-sum MFMA)
    union { short8 s; u32 w[4]; } onesU;
    onesU.w[0] = onesU.w[1] = onesU.w[2] = onesU.w[3] = 0x3F803F80u;
    const short8 ones = onesU.s;
    const floatx16 fz = (floatx16)0.0f;

    const int qb = qtile * 64;
    const int nkt = qtile + 1;

    // Q fragments (B-operand): lane holds Q[qb+qg*32+rl][dc*16+hi*8+0..7]
    short8 aq[4];
#pragma unroll
    for (int dc = 0; dc < 4; dc++)
        aq[dc] = *(const short8*)
            &Qp[(size_t)(qb + qg * 32 + rl) * DH + dc * 16 + hi * 8];

    floatx16 accO[2];
    accO[0] = fz; accO[1] = fz;
    floatx16 accL = fz;

    auto stage = [&](int kt, int tgt) {
#pragma unroll
        for (int c = 0; c < 2; c++) {
            async_cp16(&Kp[(size_t)(kt * 64 + krow) * DH + c * 32 + gofsK],
                       &Kl[tgt][c][wave * 512]);
            async_cp16(&Vp[(size_t)krow * SEQ + kt * 64 + c * 32 + gofsK],
                       &Vl[tgt][c][wave * 512]);
        }
    };

    stage(0, 0);

    auto tile = [&](auto CURc, int kt) {
        constexpr int CUR = decltype(CURc)::v;
        waitcnt_vm<0>();
        asm volatile("s_barrier" ::: "memory");
        if (kt + 1 < nkt) stage(kt + 1, CUR ^ 1);

        // keyblock - qblock offset; <0 full, ==0 diagonal, >0 masked out
        const int kq = (kt - qtile) * 64 + (ks - qg) * 32;
        if (kq <= 0) {
            // ---- QK^T: S[key][q], A = K rows, B = Q (v9-verified) ----
            floatx16 s = fz;
#pragma unroll
            for (int dc = 0; dc < 4; dc++) {
                const int p = (((dc & 1) * 2 + hi) ^ swz);
                const short8 ak = *(const short8*)
                    &Kl[CUR][dc >> 1][(ks * 32 + rl) * 32 + p * 8];
                s = __builtin_amdgcn_mfma_f32_32x32x16_bf16(ak, aq[dc], s, 0, 0, 0);
            }
            if (kq == 0) {   // diagonal: mask key_local > q_local
#pragma unroll
                for (int r = 0; r < 16; r++) {
                    const int kl = (r & 3) + 8 * (r >> 2) + 4 * hi;
                    if (kl > rl) s[r] = -1e30f;
                }
            }
#pragma unroll
            for (int r = 0; r < 16; r++) s[r] = __builtin_amdgcn_exp2f(s[r]);

            u32 u[8];
#pragma unroll
            for (int i = 0; i < 8; i++) u[i] = pk_bf16(s[2 * i], s[2 * i + 1]);

            // ---- PV + row-sum: v9's permuted shared key-order ----
#pragma unroll
            for (int ksl = 0; ksl < 2; ksl++) {
                union { short8 v; u32 w[4]; } pa;
                pa.w[0] = u[4 * ksl + 0]; pa.w[1] = u[4 * ksl + 1];
                pa.w[2] = u[4 * ksl + 2]; pa.w[3] = u[4 * ksl + 3];
                const int p1 = (2 * ksl) ^ swz;
#pragma unroll
                for (int db = 0; db < 2; db++) {
                    const int drow = db * 32 + rl;
                    union { short8 v; u32 w[4]; } bv;
                    const uint2 v1 = *(const uint2*)
                        &Vl[CUR][ks][drow * 32 + p1 * 8 + hi * 4];
                    const uint2 v2 = *(const uint2*)
                        &Vl[CUR][ks][drow * 32 + (p1 ^ 1) * 8 + hi * 4];
                    bv.w[0] = v1.x; bv.w[1] = v1.y; bv.w[2] = v2.x; bv.w[3] = v2.y;
                    accO[db] = __builtin_amdgcn_mfma_f32_32x32x16_bf16(
                        pa.v, bv.v, accO[db], 0, 0, 0);
                }
                accL = __builtin_amdgcn_mfma_f32_32x32x16_bf16(
                    pa.v, ones, accL, 0, 0, 0);
            }
        }
    };

    int kt = 0;
    while (kt + 2 <= nkt) {
        tile(IC<0>{}, kt);
        tile(IC<1>{}, kt + 1);
        kt += 2;
    }
    if (kt < nkt) tile(IC<0>{}, kt);

    // ---- cross-(key-split) reduction + normalize + store ----
    __syncthreads();                      // done reading Kl/Vl
    float* redO = (float*)&Kl[0][0][0];   // 64 rows x 64 cols f32 = 16 KB
    float* redL = (float*)&Vl[0][0][0];   // 64 f32, indexed by local q-row
    if (ks == 1) {
#pragma unroll
        for (int r = 0; r < 16; r++) {
            redO[(qg * 32 + r)      * 64 + lane] = accO[0][r];
            redO[(qg * 32 + 16 + r) * 64 + lane] = accO[1][r];
        }
        if (rl == 0) {
#pragma unroll
            for (int r = 0; r < 16; r++) {
                const int qrow = (r & 3) + 8 * (r >> 2) + 4 * hi;
                redL[qg * 32 + qrow] = accL[r];
            }
        }
    }
    __syncthreads();
    if (ks == 0) {
#pragma unroll
        for (int r = 0; r < 16; r++) {
            const int qrow = (r & 3) + 8 * (r >> 2) + 4 * hi;
            const float inv = 1.0f / (accL[r] + redL[qg * 32 + qrow]);
            const int t = qb + qg * 32 + qrow;
            const size_t base = ((size_t)b * SEQ + t) * CDIM + h * DH;
            const float o0 = accO[0][r] + redO[(qg * 32 + r)      * 64 + lane];
            const float o1 = accO[1][r] + redO[(qg * 32 + 16 + r) * 64 + lane];
            O[base + rl]      = f2bf(o0 * inv);
            O[base + 32 + rl] = f2bf(o1 * inv);
        }
    }
}

// ---------------- launch ----------------
extern "C" void kernel_launch(void* const* d_in, const int* in_sizes, int n_in,
                              void* d_out, int out_size, void* d_ws, size_t ws_size,
                              hipStream_t stream) {
    const float* x      = (const float*)d_in[0];
    const float* w_attn = (const float*)d_in[1];
    const float* b_attn = (const float*)d_in[2];
    const float* w_proj = (const float*)d_in[3];
    const float* b_proj = (const float*)d_in[4];
    float* out = (float*)d_out;

    unsigned short* xb   = (unsigned short*)d_ws;
    unsigned short* wta  = xb  + (size_t)MROWS * CDIM;
    unsigned short* wtp  = wta + (size_t)3 * CDIM * CDIM;
    unsigned short* qws  = wtp + (size_t)CDIM * CDIM;
    unsigned short* kws  = qws + (size_t)MROWS * CDIM;
    unsigned short* vtws = kws + (size_t)MROWS * CDIM;
    unsigned short* ob   = xb;

    prep_kernel<<<6720, 256, 0, stream>>>(x, xb, w_attn, wta, w_proj, wtp);

    dim3 g1(MROWS / 128, (3 * CDIM) / 128);   // 64 x 18 = 1152 (%8 == 0)
    gemm_bf16<1, CDIM, 128, 128><<<g1, 256, 0, stream>>>(
        xb, wta, b_attn, nullptr, qws, kws, vtws, 3 * CDIM);

    attn_kernel<<<1536, 256, 0, stream>>>(qws, kws, vtws, ob);

    dim3 g3(MROWS / 64, CDIM / 128);          // 128 x 6 = 768 (%8 == 0)
    gemm_bf16<0, CDIM, 64, 128><<<g3, 256, 0, stream>>>(
        ob, wtp, b_proj, out, nullptr, nullptr, nullptr, CDIM);
}

// Round 9
// 201.218 us; speedup vs baseline: 1.0276x; 1.0276x over previous
//
#include <hip/hip_runtime.h>
#include <stdint.h>

#define NHEAD 12
#define DH 64
#define BATCH 4
#define SEQ 2048
#define CDIM 768
#define MROWS (BATCH*SEQ)   // 8192

typedef __attribute__((ext_vector_type(8))) short short8;
typedef __attribute__((ext_vector_type(4))) float floatx4;
typedef __attribute__((ext_vector_type(16))) float floatx16;
typedef unsigned int u32;

template<int N> struct IC { static constexpr int v = N; };

__device__ inline unsigned short f2bf(float f) {
    union { float f; unsigned u; } v; v.f = f;
    unsigned r = v.u + 0x7FFFu + ((v.u >> 16) & 1u);
    return (unsigned short)(r >> 16);
}

__device__ __forceinline__ u32 pk_bf16(float a, float b) {
    u32 d;
    asm("v_cvt_pk_bf16_f32 %0, %1, %2" : "=v"(d) : "v"(a), "v"(b));
    return d;
}

__device__ __forceinline__ void async_cp16(const unsigned short* g, unsigned short* l) {
    __builtin_amdgcn_global_load_lds(
        (const __attribute__((address_space(1))) u32*)g,
        (__attribute__((address_space(3))) u32*)l, 16, 0, 0);
}

template<int N> __device__ __forceinline__ void waitcnt_vm() {
    if constexpr (N == 0)      asm volatile("s_waitcnt vmcnt(0)" ::: "memory");
    else if constexpr (N == 3) asm volatile("s_waitcnt vmcnt(3)" ::: "memory");
    else if constexpr (N == 4) asm volatile("s_waitcnt vmcnt(4)" ::: "memory");
}

// ---------------- fused prep: x->bf16, w_attn^T->bf16, w_proj^T->bf16 -------
__device__ __forceinline__ void transpose_tile(
    const float* __restrict__ in, unsigned short* __restrict__ out,
    int K, int N, int k0, int n0, unsigned short (*T)[72]) {
    const int t = threadIdx.x;
    const int nc = t & 63, kw = t >> 6;
    for (int i = 0; i < 16; i++) {
        const int kr = kw + i * 4;
        T[nc][kr] = f2bf(in[(size_t)(k0 + kr) * N + n0 + nc]);
    }
    __syncthreads();
    const int row = t >> 2, seg = t & 3;
    uint4 a = *(const uint4*)&T[row][seg * 16];
    uint4 b2 = *(const uint4*)&T[row][seg * 16 + 8];
    unsigned short* o = &out[(size_t)(n0 + row) * K + k0 + seg * 16];
    *(uint4*)o = a;
    *(uint4*)(o + 8) = b2;
}

__global__ __launch_bounds__(256) void prep_kernel(
    const float* __restrict__ x,      unsigned short* __restrict__ xb,
    const float* __restrict__ wa,     unsigned short* __restrict__ wta,
    const float* __restrict__ wp,     unsigned short* __restrict__ wtp) {
    __shared__ unsigned short T[64][72];
    const int lin = blockIdx.x;
    if (lin < 6144) {                      // convert x: 1024 elems/block
        const int i = (lin * 256 + threadIdx.x) * 4;
        float4 f = *(const float4*)(x + i);
        union { unsigned short s[4]; uint2 u; } p;
        p.s[0] = f2bf(f.x); p.s[1] = f2bf(f.y);
        p.s[2] = f2bf(f.z); p.s[3] = f2bf(f.w);
        *(uint2*)(xb + i) = p.u;
    } else if (lin < 6144 + 432) {         // w_attn^T (768 x 2304)
        const int t2 = lin - 6144;
        transpose_tile(wa, wta, CDIM, 3 * CDIM, (t2 % 12) * 64, (t2 / 12) * 64, T);
    } else {                               // w_proj^T (768 x 768)
        const int t3 = lin - 6576;
        transpose_tile(wp, wtp, CDIM, CDIM, (t3 % 12) * 64, (t3 / 12) * 64, T);
    }
}

// ---------------- GEMM v3: 2-buffer ring, NATURAL dispatch order -------------
// r8 lesson: gx%8==0 means natural lin%8 = bx%8 -> m-blocks already pinned to
// XCDs (A chunk 1.6MB L2-resident, B via L3). The chunked swizzle replaced
// this with per-XCD full-A sweeps (FETCH 29->114MB). Reverted. 2-buffer ring
// kept (LDS 34/24KB); hazard: buffer written at iter k (k+1 & 1) was fully
// read at iter k-1, all readers passed iter k's barrier.
// MODE 0: fp32 C. MODE 1: QKV epilogue; V-part blocks transpose via LDS.
template<int MODE, int KD, int BM, int BN>
__global__ __launch_bounds__(256) void gemm_bf16(
    const unsigned short* __restrict__ A,
    const unsigned short* __restrict__ BT,
    const float* __restrict__ bias,
    float* __restrict__ Cout,
    unsigned short* __restrict__ Qout,
    unsigned short* __restrict__ Kout,
    unsigned short* __restrict__ VTout,
    int Ndim)
{
    constexpr int TM = BM / 32, TN = BN / 32;
    constexpr int CHA = BM / 64, CHB = BN / 64;
    constexpr int RING = 2 * (BM + BN) * 32;            // shorts
    constexpr int SCR  = (MODE == 1) ? 4 * 64 * 68 : 0; // epilogue scratch
    constexpr int SHSZ = RING > SCR ? RING : SCR;
    __shared__ unsigned short SH[SHSZ];
    auto As = [&](int b2) { return &SH[b2 * BM * 32]; };
    auto Bs = [&](int b2) { return &SH[2 * BM * 32 + b2 * BN * 32]; };

    const int tid  = threadIdx.x;
    const int wave = tid >> 6;
    const int lane = tid & 63;
    const int l16  = lane & 15;
    const int quad = lane >> 4;
    const int wm = wave >> 1, wn = wave & 1;
    const int m0 = blockIdx.x * BM;
    const int n0 = blockIdx.y * BN;

    const int rloc = lane >> 2;
    const int gs   = (((lane & 3) ^ (rloc & 3) ^ ((rloc >> 2) & 3))) * 8;
    const int pg   = ((quad ^ (l16 & 3) ^ ((l16 >> 2) & 3))) * 8;

    floatx4 acc[TM][TN];
    for (int i = 0; i < TM; i++)
        for (int j = 0; j < TN; j++) acc[i][j] = (floatx4)0.0f;

    constexpr int NIT = KD / 32;

    auto stageTo = [&](int s, int buf) {
        const int koff = s * 32;
        for (int ch = 0; ch < CHA; ch++) {
            const int row = wave * CHA * 16 + ch * 16 + rloc;
            async_cp16(&A[(size_t)(m0 + row) * KD + koff + gs],
                       &As(buf)[(wave * CHA + ch) * 512]);
        }
        for (int ch = 0; ch < CHB; ch++) {
            const int row = wave * CHB * 16 + ch * 16 + rloc;
            async_cp16(&BT[(size_t)(n0 + row) * KD + koff + gs],
                       &Bs(buf)[(wave * CHB + ch) * 512]);
        }
    };
    stageTo(0, 0);

    for (int it = 0; it < NIT; it++) {
        waitcnt_vm<0>();
        asm volatile("s_barrier" ::: "memory");
        if (it + 1 < NIT) stageTo(it + 1, (it + 1) & 1);
        const int buf = it & 1;
        short8 a[TM], b[TN];
        for (int i = 0; i < TM; i++)
            a[i] = *(const short8*)&As(buf)[(wm * (BM / 2) + i * 16 + l16) * 32 + pg];
        for (int j = 0; j < TN; j++)
            b[j] = *(const short8*)&Bs(buf)[(wn * (BN / 2) + j * 16 + l16) * 32 + pg];
        for (int i = 0; i < TM; i++)
            for (int j = 0; j < TN; j++)
                acc[i][j] = __builtin_amdgcn_mfma_f32_16x16x32_bf16(
                    a[i], b[j], acc[i][j], 0, 0, 0);
    }

    const float QSCALE = 0.18033688011112042f;   // 0.125 * log2(e)

    if (MODE == 1 && (n0 / CDIM) == 2) {
        // ---- V blocks: transpose 64x64 wave tile via LDS, coalesced VT ----
        __syncthreads();                           // done reading SH
        unsigned short* scr = &SH[wave * (64 * 68)];
        for (int i = 0; i < TM; i++) {
            const int tl = i * 16 + quad * 4;
            for (int j = 0; j < TN; j++) {
                const int dl = j * 16 + l16;
                const float bv = bias[n0 + wn * 64 + j * 16 + l16];
                uint2 u;
                u.x = pk_bf16(acc[i][j][0] + bv, acc[i][j][1] + bv);
                u.y = pk_bf16(acc[i][j][2] + bv, acc[i][j][3] + bv);
                *(uint2*)&scr[dl * 68 + tl] = u;
            }
        }
        const int b_ = m0 >> 11;
        const int tg = (m0 & 2047) + wm * 64;
        const int h  = (n0 - 2 * CDIM + wn * 64) >> 6;
        const size_t rowbase = ((size_t)(b_ * NHEAD + h)) * DH;
        for (int p = 0; p < 8; p++) {
            const int d  = p * 8 + (lane >> 3);
            const int tc = (lane & 7) * 8;
            uint4 v = *(const uint4*)&scr[d * 68 + tc];
            *(uint4*)&VTout[(rowbase + d) * SEQ + tg + tc] = v;
        }
        return;
    }

    for (int i = 0; i < TM; i++) {
        const int mbase = m0 + wm * (BM / 2) + i * 16 + quad * 4;
        for (int j = 0; j < TN; j++) {
            const int ncj  = n0 + wn * (BN / 2) + j * 16;
            const int ncol = ncj + l16;
            const float bv = bias[ncol];
            for (int r = 0; r < 4; r++) {
                const int m = mbase + r;
                const float v = acc[i][j][r] + bv;
                if (MODE == 0) {
                    Cout[(size_t)m * Ndim + ncol] = v;
                } else {
                    const int part = ncj / CDIM;   // 0 or 1 here
                    const int c = ncol - part * CDIM;
                    const int hh = c >> 6, d = c & 63;
                    const int b_ = m >> 11, t = m & 2047;
                    const size_t bh = (size_t)(b_ * NHEAD + hh);
                    if (part == 0)
                        Qout[(bh * SEQ + t) * DH + d] = f2bf(v * QSCALE);
                    else
                        Kout[(bh * SEQ + t) * DH + d] = f2bf(v);
                }
            }
        }
    }
}

// ---------------- flash attention v13 (verified r6): 1536 single-pass blocks -
__global__ __launch_bounds__(256) void attn_kernel(
    const unsigned short* __restrict__ Q,
    const unsigned short* __restrict__ K,
    const unsigned short* __restrict__ VT,
    unsigned short* __restrict__ O)
{
    __shared__ unsigned short Kl[2][2][64 * 32];   // [buf][d-half][key row][32]
    __shared__ unsigned short Vl[2][2][64 * 32];   // [buf][key-half][d row][32]

    const int tid  = threadIdx.x;
    const int wave = tid >> 6;
    const int lane = tid & 63;
    const int rl   = lane & 31;
    const int hi   = lane >> 5;
    const int qg   = wave >> 1;         // q-group: rows qg*32..+31 of the 64
    const int ks   = wave & 1;          // key-split: keys ks*32..+31 of tile

    const int lin = blockIdx.x;         // 0..1535
    const int j   = lin >> 3;           // 0..191
    const int bh  = (j % 6) * 8 + (lin & 7);   // XCD-pinned: bh === lin (mod 8)
    const int qtile = 31 - (j / 6);            // heavy tiles dispatched first
    const int h = bh % NHEAD, b = bh / NHEAD;

    const unsigned short* Qp = Q  + (size_t)bh * SEQ * DH;
    const unsigned short* Kp = K  + (size_t)bh * SEQ * DH;
    const unsigned short* Vp = VT + (size_t)bh * DH * SEQ;

    const int rloc  = lane >> 2;
    const int gofsK = ((lane & 3) ^ (rloc & 3) ^ ((rloc >> 2) & 3)) * 8;
    const int krow  = wave * 16 + rloc;
    const int swz   = (rl & 3) ^ ((rl >> 2) & 3);   // group unswizzle

    // bf16 ones vector (B operand for row-sum MFMA)
    union { short8 s; u32 w[4]; } onesU;
    onesU.w[0] = onesU.w[1] = onesU.w[2] = onesU.w[3] = 0x3F803F80u;
    const short8 ones = onesU.s;
    const floatx16 fz = (floatx16)0.0f;

    const int qb = qtile * 64;
    const int nkt = qtile + 1;

    // Q fragments (B-operand): lane holds Q[qb+qg*32+rl][dc*16+hi*8+0..7]
    short8 aq[4];
#pragma unroll
    for (int dc = 0; dc < 4; dc++)
        aq[dc] = *(const short8*)
            &Qp[(size_t)(qb + qg * 32 + rl) * DH + dc * 16 + hi * 8];

    floatx16 accO[2];
    accO[0] = fz; accO[1] = fz;
    floatx16 accL = fz;

    auto stage = [&](int kt, int tgt) {
#pragma unroll
        for (int c = 0; c < 2; c++) {
            async_cp16(&Kp[(size_t)(kt * 64 + krow) * DH + c * 32 + gofsK],
                       &Kl[tgt][c][wave * 512]);
            async_cp16(&Vp[(size_t)krow * SEQ + kt * 64 + c * 32 + gofsK],
                       &Vl[tgt][c][wave * 512]);
        }
    };

    stage(0, 0);

    auto tile = [&](auto CURc, int kt) {
        constexpr int CUR = decltype(CURc)::v;
        waitcnt_vm<0>();
        asm volatile("s_barrier" ::: "memory");
        if (kt + 1 < nkt) stage(kt + 1, CUR ^ 1);

        // keyblock - qblock offset; <0 full, ==0 diagonal, >0 masked out
        const int kq = (kt - qtile) * 64 + (ks - qg) * 32;
        if (kq <= 0) {
            // ---- QK^T: S[key][q], A = K rows, B = Q (v9-verified) ----
            floatx16 s = fz;
#pragma unroll
            for (int dc = 0; dc < 4; dc++) {
                const int p = (((dc & 1) * 2 + hi) ^ swz);
                const short8 ak = *(const short8*)
                    &Kl[CUR][dc >> 1][(ks * 32 + rl) * 32 + p * 8];
                s = __builtin_amdgcn_mfma_f32_32x32x16_bf16(ak, aq[dc], s, 0, 0, 0);
            }
            if (kq == 0) {   // diagonal: mask key_local > q_local
#pragma unroll
                for (int r = 0; r < 16; r++) {
                    const int kl = (r & 3) + 8 * (r >> 2) + 4 * hi;
                    if (kl > rl) s[r] = -1e30f;
                }
            }
#pragma unroll
            for (int r = 0; r < 16; r++) s[r] = __builtin_amdgcn_exp2f(s[r]);

            u32 u[8];
#pragma unroll
            for (int i = 0; i < 8; i++) u[i] = pk_bf16(s[2 * i], s[2 * i + 1]);

            // ---- PV + row-sum: v9's permuted shared key-order ----
#pragma unroll
            for (int ksl = 0; ksl < 2; ksl++) {
                union { short8 v; u32 w[4]; } pa;
                pa.w[0] = u[4 * ksl + 0]; pa.w[1] = u[4 * ksl + 1];
                pa.w[2] = u[4 * ksl + 2]; pa.w[3] = u[4 * ksl + 3];
                const int p1 = (2 * ksl) ^ swz;
#pragma unroll
                for (int db = 0; db < 2; db++) {
                    const int drow = db * 32 + rl;
                    union { short8 v; u32 w[4]; } bv;
                    const uint2 v1 = *(const uint2*)
                        &Vl[CUR][ks][drow * 32 + p1 * 8 + hi * 4];
                    const uint2 v2 = *(const uint2*)
                        &Vl[CUR][ks][drow * 32 + (p1 ^ 1) * 8 + hi * 4];
                    bv.w[0] = v1.x; bv.w[1] = v1.y; bv.w[2] = v2.x; bv.w[3] = v2.y;
                    accO[db] = __builtin_amdgcn_mfma_f32_32x32x16_bf16(
                        pa.v, bv.v, accO[db], 0, 0, 0);
                }
                accL = __builtin_amdgcn_mfma_f32_32x32x16_bf16(
                    pa.v, ones, accL, 0, 0, 0);
            }
        }
    };

    int kt = 0;
    while (kt + 2 <= nkt) {
        tile(IC<0>{}, kt);
        tile(IC<1>{}, kt + 1);
        kt += 2;
    }
    if (kt < nkt) tile(IC<0>{}, kt);

    // ---- cross-(key-split) reduction + normalize + store ----
    __syncthreads();                      // done reading Kl/Vl
    float* redO = (float*)&Kl[0][0][0];   // 64 rows x 64 cols f32 = 16 KB
    float* redL = (float*)&Vl[0][0][0];   // 64 f32, indexed by local q-row
    if (ks == 1) {
#pragma unroll
        for (int r = 0; r < 16; r++) {
            redO[(qg * 32 + r)      * 64 + lane] = accO[0][r];
            redO[(qg * 32 + 16 + r) * 64 + lane] = accO[1][r];
        }
        if (rl == 0) {
#pragma unroll
            for (int r = 0; r < 16; r++) {
                const int qrow = (r & 3) + 8 * (r >> 2) + 4 * hi;
                redL[qg * 32 + qrow] = accL[r];
            }
        }
    }
    __syncthreads();
    if (ks == 0) {
#pragma unroll
        for (int r = 0; r < 16; r++) {
            const int qrow = (r & 3) + 8 * (r >> 2) + 4 * hi;
            const float inv = 1.0f / (accL[r] + redL[qg * 32 + qrow]);
            const int t = qb + qg * 32 + qrow;
            const size_t base = ((size_t)b * SEQ + t) * CDIM + h * DH;
            const float o0 = accO[0][r] + redO[(qg * 32 + r)      * 64 + lane];
            const float o1 = accO[1][r] + redO[(qg * 32 + 16 + r) * 64 + lane];
            O[base + rl]      = f2bf(o0 * inv);
            O[base + 32 + rl] = f2bf(o1 * inv);
        }
    }
}

// ---------------- launch ----------------
extern "C" void kernel_launch(void* const* d_in, const int* in_sizes, int n_in,
                              void* d_out, int out_size, void* d_ws, size_t ws_size,
                              hipStream_t stream) {
    const float* x      = (const float*)d_in[0];
    const float* w_attn = (const float*)d_in[1];
    const float* b_attn = (const float*)d_in[2];
    const float* w_proj = (const float*)d_in[3];
    const float* b_proj = (const float*)d_in[4];
    float* out = (float*)d_out;

    unsigned short* xb   = (unsigned short*)d_ws;
    unsigned short* wta  = xb  + (size_t)MROWS * CDIM;
    unsigned short* wtp  = wta + (size_t)3 * CDIM * CDIM;
    unsigned short* qws  = wtp + (size_t)CDIM * CDIM;
    unsigned short* kws  = qws + (size_t)MROWS * CDIM;
    unsigned short* vtws = kws + (size_t)MROWS * CDIM;
    unsigned short* ob   = xb;

    prep_kernel<<<6720, 256, 0, stream>>>(x, xb, w_attn, wta, w_proj, wtp);

    dim3 g1(MROWS / 128, (3 * CDIM) / 128);   // 64 x 18, gx%8==0 -> natural XCD pin
    gemm_bf16<1, CDIM, 128, 128><<<g1, 256, 0, stream>>>(
        xb, wta, b_attn, nullptr, qws, kws, vtws, 3 * CDIM);

    attn_kernel<<<1536, 256, 0, stream>>>(qws, kws, vtws, ob);

    dim3 g3(MROWS / 64, CDIM / 128);          // 128 x 6, gx%8==0 -> natural XCD pin
    gemm_bf16<0, CDIM, 64, 128><<<g3, 256, 0, stream>>>(
        ob, wtp, b_proj, out, nullptr, nullptr, nullptr, CDIM);
}

// Round 10
// 193.416 us; speedup vs baseline: 1.0691x; 1.0403x over previous
//
#include <hip/hip_runtime.h>
#include <stdint.h>

#define NHEAD 12
#define DH 64
#define BATCH 4
#define SEQ 2048
#define CDIM 768
#define MROWS (BATCH*SEQ)   // 8192

typedef __attribute__((ext_vector_type(8))) short short8;
typedef __attribute__((ext_vector_type(4))) float floatx4;
typedef __attribute__((ext_vector_type(16))) float floatx16;
typedef unsigned int u32;

template<int N> struct IC { static constexpr int v = N; };

__device__ inline unsigned short f2bf(float f) {
    union { float f; unsigned u; } v; v.f = f;
    unsigned r = v.u + 0x7FFFu + ((v.u >> 16) & 1u);
    return (unsigned short)(r >> 16);
}

__device__ __forceinline__ u32 pk_bf16(float a, float b) {
    u32 d;
    asm("v_cvt_pk_bf16_f32 %0, %1, %2" : "=v"(d) : "v"(a), "v"(b));
    return d;
}

__device__ __forceinline__ void async_cp16(const unsigned short* g, unsigned short* l) {
    __builtin_amdgcn_global_load_lds(
        (const __attribute__((address_space(1))) u32*)g,
        (__attribute__((address_space(3))) u32*)l, 16, 0, 0);
}

template<int N> __device__ __forceinline__ void waitcnt_vm() {
    if constexpr (N == 0)      asm volatile("s_waitcnt vmcnt(0)" ::: "memory");
    else if constexpr (N == 3) asm volatile("s_waitcnt vmcnt(3)" ::: "memory");
    else if constexpr (N == 4) asm volatile("s_waitcnt vmcnt(4)" ::: "memory");
}

// ---------------- fused prep: x->bf16, w_attn^T->bf16, w_proj^T->bf16 -------
__device__ __forceinline__ void transpose_tile(
    const float* __restrict__ in, unsigned short* __restrict__ out,
    int K, int N, int k0, int n0, unsigned short (*T)[72]) {
    const int t = threadIdx.x;
    const int nc = t & 63, kw = t >> 6;
    for (int i = 0; i < 16; i++) {
        const int kr = kw + i * 4;
        T[nc][kr] = f2bf(in[(size_t)(k0 + kr) * N + n0 + nc]);
    }
    __syncthreads();
    const int row = t >> 2, seg = t & 3;
    uint4 a = *(const uint4*)&T[row][seg * 16];
    uint4 b2 = *(const uint4*)&T[row][seg * 16 + 8];
    unsigned short* o = &out[(size_t)(n0 + row) * K + k0 + seg * 16];
    *(uint4*)o = a;
    *(uint4*)(o + 8) = b2;
}

__global__ __launch_bounds__(256) void prep_kernel(
    const float* __restrict__ x,      unsigned short* __restrict__ xb,
    const float* __restrict__ wa,     unsigned short* __restrict__ wta,
    const float* __restrict__ wp,     unsigned short* __restrict__ wtp) {
    __shared__ unsigned short T[64][72];
    const int lin = blockIdx.x;
    if (lin < 6144) {                      // convert x: 1024 elems/block
        const int i = (lin * 256 + threadIdx.x) * 4;
        float4 f = *(const float4*)(x + i);
        union { unsigned short s[4]; uint2 u; } p;
        p.s[0] = f2bf(f.x); p.s[1] = f2bf(f.y);
        p.s[2] = f2bf(f.z); p.s[3] = f2bf(f.w);
        *(uint2*)(xb + i) = p.u;
    } else if (lin < 6144 + 432) {         // w_attn^T (768 x 2304)
        const int t2 = lin - 6144;
        transpose_tile(wa, wta, CDIM, 3 * CDIM, (t2 % 12) * 64, (t2 / 12) * 64, T);
    } else {                               // w_proj^T (768 x 768)
        const int t3 = lin - 6576;
        transpose_tile(wp, wtp, CDIM, CDIM, (t3 % 12) * 64, (t3 / 12) * 64, T);
    }
}

// ---------------- GEMM v4: WAVES-parametric, 3-buffer counted-vmcnt ring -----
// r9 lesson: GEMM is exposed-serial-chain bound (~1.2k cy/iter vs 250 issue,
// ~1 wave/SIMD resident). Fix inside the block: WAVES=8 (512 thr) for the QKV
// gemm -> >=2 waves/SIMD even at 1 resident block; 256x128 tile keeps per-wave
// 64x64 (TM=TN=4, identical MFMA/read pattern). DEPTH=3 ring + vmcnt(3)
// counted prefetch = r6's proven best. Natural dispatch (gx%8==0) keeps
// m-chunks XCD-pinned (A 1.6MB L2-resident/XCD; r8 lesson: don't swizzle).
// Wave map: WC=2 col-groups, WR=WAVES/2 row-groups; per-wave PR=BM/WR x PC=64.
// MODE 0: fp32 C. MODE 1: QKV epilogue; V-part blocks transpose via LDS.
template<int MODE, int KD, int BM, int BN, int WAVES>
__global__ __launch_bounds__(WAVES * 64) void gemm_bf16(
    const unsigned short* __restrict__ A,
    const unsigned short* __restrict__ BT,
    const float* __restrict__ bias,
    float* __restrict__ Cout,
    unsigned short* __restrict__ Qout,
    unsigned short* __restrict__ Kout,
    unsigned short* __restrict__ VTout,
    int Ndim)
{
    constexpr int WC = 2, WR = WAVES / WC;
    constexpr int PR = BM / WR, PC = BN / WC;      // per-wave tile
    constexpr int TM = PR / 16, TN = PC / 16;
    constexpr int CHA = BM / (16 * WAVES), CHB = BN / (16 * WAVES);
    constexpr int DEPTH = 3;
    constexpr int RING = DEPTH * (BM + BN) * 32;         // shorts
    constexpr int SCR  = (MODE == 1) ? WAVES * 64 * 68 : 0;
    constexpr int SHSZ = RING > SCR ? RING : SCR;
    __shared__ unsigned short SH[SHSZ];
    auto As = [&](int bb) { return &SH[bb * BM * 32]; };
    auto Bs = [&](int bb) { return &SH[DEPTH * BM * 32 + bb * BN * 32]; };

    const int tid  = threadIdx.x;
    const int wave = tid >> 6;
    const int lane = tid & 63;
    const int l16  = lane & 15;
    const int quad = lane >> 4;
    const int wm = wave >> 1, wn = wave & 1;      // WC==2: wn in {0,1}
    const int m0 = blockIdx.x * BM;
    const int n0 = blockIdx.y * BN;

    const int rloc = lane >> 2;
    const int gs   = (((lane & 3) ^ (rloc & 3) ^ ((rloc >> 2) & 3))) * 8;
    const int pg   = ((quad ^ (l16 & 3) ^ ((l16 >> 2) & 3))) * 8;

    floatx4 acc[TM][TN];
    for (int i = 0; i < TM; i++)
        for (int j = 0; j < TN; j++) acc[i][j] = (floatx4)0.0f;

    constexpr int NIT = KD / 32;

    auto stageTo = [&](int s, int buf) {
        const int koff = s * 32;
        for (int ch = 0; ch < CHA; ch++) {
            const int row = wave * CHA * 16 + ch * 16 + rloc;
            async_cp16(&A[(size_t)(m0 + row) * KD + koff + gs],
                       &As(buf)[(wave * CHA + ch) * 512]);
        }
        for (int ch = 0; ch < CHB; ch++) {
            const int row = wave * CHB * 16 + ch * 16 + rloc;
            async_cp16(&BT[(size_t)(n0 + row) * KD + koff + gs],
                       &Bs(buf)[(wave * CHB + ch) * 512]);
        }
    };
    stageTo(0, 0);
    stageTo(1, 1);

    for (int it = 0; it < NIT; it++) {
        if (it < NIT - 1) waitcnt_vm<CHA + CHB>();   // tile it done, it+1 in flight
        else              waitcnt_vm<0>();
        asm volatile("s_barrier" ::: "memory");
        if (it + 2 < NIT) {
            int b2 = it + 2; b2 -= (b2 / DEPTH) * DEPTH;
            stageTo(it + 2, b2);
        }
        int buf = it; buf -= (buf / DEPTH) * DEPTH;
        short8 a[TM], b[TN];
        for (int i = 0; i < TM; i++)
            a[i] = *(const short8*)&As(buf)[(wm * PR + i * 16 + l16) * 32 + pg];
        for (int j = 0; j < TN; j++)
            b[j] = *(const short8*)&Bs(buf)[(wn * PC + j * 16 + l16) * 32 + pg];
        for (int i = 0; i < TM; i++)
            for (int j = 0; j < TN; j++)
                acc[i][j] = __builtin_amdgcn_mfma_f32_16x16x32_bf16(
                    a[i], b[j], acc[i][j], 0, 0, 0);
    }

    const float QSCALE = 0.18033688011112042f;   // 0.125 * log2(e)

    if (MODE == 1 && (n0 / CDIM) == 2) {
        // ---- V blocks: transpose 64x64 wave tile via LDS, coalesced VT ----
        __syncthreads();                           // done reading SH
        unsigned short* scr = &SH[wave * (64 * 68)];
        for (int i = 0; i < TM; i++) {
            const int tl = i * 16 + quad * 4;
            for (int j = 0; j < TN; j++) {
                const int dl = j * 16 + l16;
                const float bv = bias[n0 + wn * PC + j * 16 + l16];
                uint2 u;
                u.x = pk_bf16(acc[i][j][0] + bv, acc[i][j][1] + bv);
                u.y = pk_bf16(acc[i][j][2] + bv, acc[i][j][3] + bv);
                *(uint2*)&scr[dl * 68 + tl] = u;
            }
        }
        const int b_ = m0 >> 11;
        const int tg = (m0 & 2047) + wm * PR;
        const int h  = (n0 - 2 * CDIM + wn * PC) >> 6;
        const size_t rowbase = ((size_t)(b_ * NHEAD + h)) * DH;
        for (int p = 0; p < 8; p++) {
            const int d  = p * 8 + (lane >> 3);
            const int tc = (lane & 7) * 8;
            uint4 v = *(const uint4*)&scr[d * 68 + tc];
            *(uint4*)&VTout[(rowbase + d) * SEQ + tg + tc] = v;
        }
        return;
    }

    for (int i = 0; i < TM; i++) {
        const int mbase = m0 + wm * PR + i * 16 + quad * 4;
        for (int j = 0; j < TN; j++) {
            const int ncj  = n0 + wn * PC + j * 16;
            const int ncol = ncj + l16;
            const float bv = bias[ncol];
            for (int r = 0; r < 4; r++) {
                const int m = mbase + r;
                const float v = acc[i][j][r] + bv;
                if (MODE == 0) {
                    Cout[(size_t)m * Ndim + ncol] = v;
                } else {
                    const int part = ncj / CDIM;   // 0 or 1 here
                    const int c = ncol - part * CDIM;
                    const int hh = c >> 6, d = c & 63;
                    const int b_ = m >> 11, t = m & 2047;
                    const size_t bh = (size_t)(b_ * NHEAD + hh);
                    if (part == 0)
                        Qout[(bh * SEQ + t) * DH + d] = f2bf(v * QSCALE);
                    else
                        Kout[(bh * SEQ + t) * DH + d] = f2bf(v);
                }
            }
        }
    }
}

// ---------------- flash attention v13 (verified r6): 1536 single-pass blocks -
__global__ __launch_bounds__(256) void attn_kernel(
    const unsigned short* __restrict__ Q,
    const unsigned short* __restrict__ K,
    const unsigned short* __restrict__ VT,
    unsigned short* __restrict__ O)
{
    __shared__ unsigned short Kl[2][2][64 * 32];   // [buf][d-half][key row][32]
    __shared__ unsigned short Vl[2][2][64 * 32];   // [buf][key-half][d row][32]

    const int tid  = threadIdx.x;
    const int wave = tid >> 6;
    const int lane = tid & 63;
    const int rl   = lane & 31;
    const int hi   = lane >> 5;
    const int qg   = wave >> 1;         // q-group: rows qg*32..+31 of the 64
    const int ks   = wave & 1;          // key-split: keys ks*32..+31 of tile

    const int lin = blockIdx.x;         // 0..1535
    const int j   = lin >> 3;           // 0..191
    const int bh  = (j % 6) * 8 + (lin & 7);   // XCD-pinned: bh === lin (mod 8)
    const int qtile = 31 - (j / 6);            // heavy tiles dispatched first
    const int h = bh % NHEAD, b = bh / NHEAD;

    const unsigned short* Qp = Q  + (size_t)bh * SEQ * DH;
    const unsigned short* Kp = K  + (size_t)bh * SEQ * DH;
    const unsigned short* Vp = VT + (size_t)bh * DH * SEQ;

    const int rloc  = lane >> 2;
    const int gofsK = ((lane & 3) ^ (rloc & 3) ^ ((rloc >> 2) & 3)) * 8;
    const int krow  = wave * 16 + rloc;
    const int swz   = (rl & 3) ^ ((rl >> 2) & 3);   // group unswizzle

    // bf16 ones vector (B operand for row-sum MFMA)
    union { short8 s; u32 w[4]; } onesU;
    onesU.w[0] = onesU.w[1] = onesU.w[2] = onesU.w[3] = 0x3F803F80u;
    const short8 ones = onesU.s;
    const floatx16 fz = (floatx16)0.0f;

    const int qb = qtile * 64;
    const int nkt = qtile + 1;

    // Q fragments (B-operand): lane holds Q[qb+qg*32+rl][dc*16+hi*8+0..7]
    short8 aq[4];
#pragma unroll
    for (int dc = 0; dc < 4; dc++)
        aq[dc] = *(const short8*)
            &Qp[(size_t)(qb + qg * 32 + rl) * DH + dc * 16 + hi * 8];

    floatx16 accO[2];
    accO[0] = fz; accO[1] = fz;
    floatx16 accL = fz;

    auto stage = [&](int kt, int tgt) {
#pragma unroll
        for (int c = 0; c < 2; c++) {
            async_cp16(&Kp[(size_t)(kt * 64 + krow) * DH + c * 32 + gofsK],
                       &Kl[tgt][c][wave * 512]);
            async_cp16(&Vp[(size_t)krow * SEQ + kt * 64 + c * 32 + gofsK],
                       &Vl[tgt][c][wave * 512]);
        }
    };

    stage(0, 0);

    auto tile = [&](auto CURc, int kt) {
        constexpr int CUR = decltype(CURc)::v;
        waitcnt_vm<0>();
        asm volatile("s_barrier" ::: "memory");
        if (kt + 1 < nkt) stage(kt + 1, CUR ^ 1);

        // keyblock - qblock offset; <0 full, ==0 diagonal, >0 masked out
        const int kq = (kt - qtile) * 64 + (ks - qg) * 32;
        if (kq <= 0) {
            // ---- QK^T: S[key][q], A = K rows, B = Q (v9-verified) ----
            floatx16 s = fz;
#pragma unroll
            for (int dc = 0; dc < 4; dc++) {
                const int p = (((dc & 1) * 2 + hi) ^ swz);
                const short8 ak = *(const short8*)
                    &Kl[CUR][dc >> 1][(ks * 32 + rl) * 32 + p * 8];
                s = __builtin_amdgcn_mfma_f32_32x32x16_bf16(ak, aq[dc], s, 0, 0, 0);
            }
            if (kq == 0) {   // diagonal: mask key_local > q_local
#pragma unroll
                for (int r = 0; r < 16; r++) {
                    const int kl = (r & 3) + 8 * (r >> 2) + 4 * hi;
                    if (kl > rl) s[r] = -1e30f;
                }
            }
#pragma unroll
            for (int r = 0; r < 16; r++) s[r] = __builtin_amdgcn_exp2f(s[r]);

            u32 u[8];
#pragma unroll
            for (int i = 0; i < 8; i++) u[i] = pk_bf16(s[2 * i], s[2 * i + 1]);

            // ---- PV + row-sum: v9's permuted shared key-order ----
#pragma unroll
            for (int ksl = 0; ksl < 2; ksl++) {
                union { short8 v; u32 w[4]; } pa;
                pa.w[0] = u[4 * ksl + 0]; pa.w[1] = u[4 * ksl + 1];
                pa.w[2] = u[4 * ksl + 2]; pa.w[3] = u[4 * ksl + 3];
                const int p1 = (2 * ksl) ^ swz;
#pragma unroll
                for (int db = 0; db < 2; db++) {
                    const int drow = db * 32 + rl;
                    union { short8 v; u32 w[4]; } bv;
                    const uint2 v1 = *(const uint2*)
                        &Vl[CUR][ks][drow * 32 + p1 * 8 + hi * 4];
                    const uint2 v2 = *(const uint2*)
                        &Vl[CUR][ks][drow * 32 + (p1 ^ 1) * 8 + hi * 4];
                    bv.w[0] = v1.x; bv.w[1] = v1.y; bv.w[2] = v2.x; bv.w[3] = v2.y;
                    accO[db] = __builtin_amdgcn_mfma_f32_32x32x16_bf16(
                        pa.v, bv.v, accO[db], 0, 0, 0);
                }
                accL = __builtin_amdgcn_mfma_f32_32x32x16_bf16(
                    pa.v, ones, accL, 0, 0, 0);
            }
        }
    };

    int kt = 0;
    while (kt + 2 <= nkt) {
        tile(IC<0>{}, kt);
        tile(IC<1>{}, kt + 1);
        kt += 2;
    }
    if (kt < nkt) tile(IC<0>{}, kt);

    // ---- cross-(key-split) reduction + normalize + store ----
    __syncthreads();                      // done reading Kl/Vl
    float* redO = (float*)&Kl[0][0][0];   // 64 rows x 64 cols f32 = 16 KB
    float* redL = (float*)&Vl[0][0][0];   // 64 f32, indexed by local q-row
    if (ks == 1) {
#pragma unroll
        for (int r = 0; r < 16; r++) {
            redO[(qg * 32 + r)      * 64 + lane] = accO[0][r];
            redO[(qg * 32 + 16 + r) * 64 + lane] = accO[1][r];
        }
        if (rl == 0) {
#pragma unroll
            for (int r = 0; r < 16; r++) {
                const int qrow = (r & 3) + 8 * (r >> 2) + 4 * hi;
                redL[qg * 32 + qrow] = accL[r];
            }
        }
    }
    __syncthreads();
    if (ks == 0) {
#pragma unroll
        for (int r = 0; r < 16; r++) {
            const int qrow = (r & 3) + 8 * (r >> 2) + 4 * hi;
            const float inv = 1.0f / (accL[r] + redL[qg * 32 + qrow]);
            const int t = qb + qg * 32 + qrow;
            const size_t base = ((size_t)b * SEQ + t) * CDIM + h * DH;
            const float o0 = accO[0][r] + redO[(qg * 32 + r)      * 64 + lane];
            const float o1 = accO[1][r] + redO[(qg * 32 + 16 + r) * 64 + lane];
            O[base + rl]      = f2bf(o0 * inv);
            O[base + 32 + rl] = f2bf(o1 * inv);
        }
    }
}

// ---------------- launch ----------------
extern "C" void kernel_launch(void* const* d_in, const int* in_sizes, int n_in,
                              void* d_out, int out_size, void* d_ws, size_t ws_size,
                              hipStream_t stream) {
    const float* x      = (const float*)d_in[0];
    const float* w_attn = (const float*)d_in[1];
    const float* b_attn = (const float*)d_in[2];
    const float* w_proj = (const float*)d_in[3];
    const float* b_proj = (const float*)d_in[4];
    float* out = (float*)d_out;

    unsigned short* xb   = (unsigned short*)d_ws;
    unsigned short* wta  = xb  + (size_t)MROWS * CDIM;
    unsigned short* wtp  = wta + (size_t)3 * CDIM * CDIM;
    unsigned short* qws  = wtp + (size_t)CDIM * CDIM;
    unsigned short* kws  = qws + (size_t)MROWS * CDIM;
    unsigned short* vtws = kws + (size_t)MROWS * CDIM;
    unsigned short* ob   = xb;

    prep_kernel<<<6720, 256, 0, stream>>>(x, xb, w_attn, wta, w_proj, wtp);

    dim3 g1(MROWS / 256, (3 * CDIM) / 128);   // 32 x 18, gx%8==0 -> natural XCD pin
    gemm_bf16<1, CDIM, 256, 128, 8><<<g1, 512, 0, stream>>>(
        xb, wta, b_attn, nullptr, qws, kws, vtws, 3 * CDIM);

    attn_kernel<<<1536, 256, 0, stream>>>(qws, kws, vtws, ob);

    dim3 g3(MROWS / 64, CDIM / 128);          // 128 x 6, gx%8==0 -> natural XCD pin
    gemm_bf16<0, CDIM, 64, 128, 4><<<g3, 256, 0, stream>>>(
        ob, wtp, b_proj, out, nullptr, nullptr, nullptr, CDIM);
}